// Round 16
// baseline (373.032 us; speedup 1.0000x reference)
//
#include <hip/hip_runtime.h>

// Top2Gating, S=8192, E=64, capacity=256. Output f32 flat, NATURAL layout:
//   [ l_aux (1) | combine (S*E*CAP) | dispatch (S*E*CAP) ] = 1 + 2*SEC words.
// 5-kernel pipeline, all scratch in d_ws (~200KB):
//   gate -> PK/G1/G2/H12/ME tables; scan -> B12 bases + l_aux;
//   fill (63 unchecked sweeps) + fill_tail (bounded final sweep) = pure
//   fillBufferAligned clone zeroing words [1, 2*SEC]; scatter -> <=4 nonzero
//   stores per token + l_aux, after the fill (stream order).

namespace {
constexpr int  TOK  = 8192;
constexpr int  NEXP = 64;
constexpr int  CAPC = 256;
constexpr int  CHK  = 64;                           // one wave per chunk rank-phase
constexpr int  NCHK = TOK / CHK;                    // 128
constexpr long long TBLK = (long long)NEXP * CAPC;  // 16384 words per token block
constexpr long long SEC  = (long long)TOK * TBLK;   // words per dense section
constexpr float NEGMIN = -3.402823466e38f;          // finfo(f32).min
constexpr float EPSF   = 1.1920929e-7f;             // finfo(f32).eps
// d_ws word offsets
constexpr int PKO  = 0;          // pk[8192]  = i1|i2<<8|r1<<16|r2<<24
constexpr int G1O  = 8192;       // gate1[8192]
constexpr int G2O  = 16384;      // gate2[8192]
constexpr int H12O = 24576;      // (h1|h2<<16)[128*64]
constexpr int MEO  = 32768;      // me[128*64]
constexpr int B12O = 40960;      // (b1|b2full<<16)[128*64]
constexpr int LAUX = 49152;      // l_aux scalar
constexpr int FILL_BLOCKS = 4096;
constexpr long long FILL_SPAN = (long long)FILL_BLOCKS * 256;   // 1,048,576 quads/sweep
}

typedef float f32x4 __attribute__((ext_vector_type(4)));

__device__ __forceinline__ float wave_max64(float v) {
    for (int o = 32; o; o >>= 1) v = fmaxf(v, __shfl_xor(v, o));
    return v;
}
__device__ __forceinline__ float wave_sum64(float v) {
    for (int o = 32; o; o >>= 1) v += __shfl_xor(v, o);
    return v;
}

// ---- Phase 1: gating + one-wave ballot-match ranks. 128 blocks x 512 threads.
__global__ __launch_bounds__(512) void tg_gate(const float* __restrict__ logits,
                                               const float* __restrict__ noise,
                                               int* __restrict__ wsi,
                                               float* __restrict__ wsf)
{
    __shared__ int   i12s[CHK];
    __shared__ float g1s[CHK], g2s[CHK];
    __shared__ int   lr1s[CHK], lr2s[CHK];
    __shared__ int   cnt[2][NEXP];
    __shared__ float meSh[512];
    const int tid = threadIdx.x, lane = tid & 63, wv = tid >> 6;   // 8 waves
    const int c = blockIdx.x;

    if (tid < 128) cnt[tid >> 6][tid & 63] = 0;

    float meAcc = 0.f;
    #pragma unroll
    for (int i = 0; i < CHK / 8; ++i) {             // 8 rows per wave
        const int rloc = i * 8 + wv;
        const int row  = c * CHK + rloc;
        const float l = logits[row * NEXP + lane];
        const float n = noise [row * NEXP + lane];

        const float m    = wave_max64(l);
        const float ex   = __expf(l - m);
        const float sm   = wave_sum64(ex);
        const float gate = ex / sm;

        const unsigned long long b1 = __ballot(l == m);     // argmax(gates)==argmax(logits)
        const int   i1 = __ffsll(b1) - 1;                   // first max wins
        const float G1 = __shfl(gate, i1);

        const float lw = (lane == i1) ? NEGMIN : (l + n);   // mask winner with finfo.min
        const float m2 = wave_max64(lw);
        const unsigned long long b2 = __ballot(lw == m2);
        const int   i2 = __ffsll(b2) - 1;
        const float G2 = __shfl(gate, i2);

        if (lane == 0) {
            i12s[rloc] = i1 | (i2 << 8);
            g1s[rloc]  = G1;
            g2s[rloc]  = G2;
        }
        meAcc += gate;
    }
    meSh[tid] = meAcc;
    __syncthreads();

    // match phase: wave 0 = first choice, wave 1 = second; chunk == one wave.
    if (wv < 2) {
        const int sel = wv;
        const int pk  = i12s[lane];
        const int e   = sel ? ((pk >> 8) & 255) : (pk & 255);
        unsigned long long m = ~0ull;
        #pragma unroll
        for (int b = 0; b < 6; ++b) {
            const unsigned long long bb = __ballot((e >> b) & 1);
            m &= ((e >> b) & 1) ? bb : ~bb;         // lanes choosing same expert
        }
        const unsigned long long below = (1ull << lane) - 1;
        (sel ? lr2s : lr1s)[lane] = __popcll(m & below);    // rank among earlier tokens
        if ((m & below) == 0) cnt[sel][e] = __popcll(m);    // leader records group size
    }
    __syncthreads();

    if (tid < CHK) {
        const int pk = i12s[tid];
        wsi[PKO + c * CHK + tid] = (pk & 0xffff) | (lr1s[tid] << 16) | (lr2s[tid] << 24);
        wsf[G1O + c * CHK + tid] = g1s[tid];
        wsf[G2O + c * CHK + tid] = g2s[tid];
    }
    if (tid < NEXP) {
        wsi[H12O + c * NEXP + tid] = cnt[0][tid] | (cnt[1][tid] << 16);
        float s = 0.f;
        #pragma unroll
        for (int w = 0; w < 8; ++w) s += meSh[w * 64 + tid];
        wsf[MEO + c * NEXP + tid] = s;
    }
}

// ---- Phase 2: PARALLEL cross-chunk scan. 256 threads = 4 quarters x 64 experts.
__global__ __launch_bounds__(256) void tg_scan(int* __restrict__ wsi,
                                               float* __restrict__ wsf)
{
    __shared__ int   s1[4][NEXP], s2[4][NEXP];
    __shared__ float sm[4][NEXP];
    const int tid = threadIdx.x, e = tid & 63, q = tid >> 6;

    int t1 = 0, t2 = 0;
    float ms = 0.f;
    #pragma unroll
    for (int i = 0; i < NCHK / 4; ++i) {            // quarter totals (32 indep loads)
        const int c = q * (NCHK / 4) + i;
        const int h = wsi[H12O + c * NEXP + e];
        t1 += h & 0xffff;
        t2 += h >> 16;
        ms += wsf[MEO + c * NEXP + e];
    }
    s1[q][e] = t1; s2[q][e] = t2; sm[q][e] = ms;
    __syncthreads();

    int off1 = 0, off2 = 0, T1 = 0;
    float MS = 0.f;
    #pragma unroll
    for (int qq = 0; qq < 4; ++qq) {                // exclusive quarter offsets + totals
        if (qq < q) { off1 += s1[qq][e]; off2 += s2[qq][e]; }
        T1 += s1[qq][e];
        MS += sm[qq][e];
    }

    int p1 = off1, p2 = T1 + off2;                  // b2full = excl prefix2 + tot1
    #pragma unroll
    for (int i = 0; i < NCHK / 4; ++i) {            // write bases (re-reads L2-hot)
        const int c = q * (NCHK / 4) + i;
        const int h = wsi[H12O + c * NEXP + e];
        wsi[B12O + c * NEXP + e] = p1 | (p2 << 16);
        p1 += h & 0xffff;
        p2 += h >> 16;
    }

    if (q == 0) {                                   // l_aux scalar
        float term = (MS * (1.f / TOK)) * ((float)T1 * (1.f / TOK)) * (float)(NEXP * NEXP);
        term = wave_sum64(term);
        if (e == 0) wsf[LAUX] = term * (1.f / NEXP);
    }
}

// ---- Phase 3a: pure fill clone, 63 unchecked sweeps of 1M quads.
//      Covers words [4, 4 + 63*4M). No loads, no branches, plain stores.
__global__ __launch_bounds__(256) void tg_fill(float* __restrict__ out)
{
    const long long idx = (long long)blockIdx.x * 256 + threadIdx.x;
    f32x4* o4 = (f32x4*)(out + 4);                  // out is 16B-aligned => out+4 too
    const f32x4 z = {0.f, 0.f, 0.f, 0.f};
    #pragma unroll
    for (int i = 0; i < 63; ++i)
        o4[idx + (long long)i * FILL_SPAN] = z;
    if (idx == 0) { out[1] = 0.f; out[2] = 0.f; out[3] = 0.f; }
}

// ---- Phase 3b: bounded final sweep. Covers words [4 + 63*4M, 2*SEC].
__global__ __launch_bounds__(256) void tg_fill_tail(float* __restrict__ out)
{
    const long long idx = (long long)blockIdx.x * 256 + threadIdx.x;
    const long long word = 4 + 63LL * FILL_SPAN * 4 + idx * 4;
    if (word + 3 <= 2 * SEC) {
        *(f32x4*)(out + word) = f32x4{0.f, 0.f, 0.f, 0.f};
    } else if (word <= 2 * SEC) {
        for (long long q = word; q <= 2 * SEC; ++q) out[q] = 0.f;
    }
}

// ---- Phase 4: scatter. One thread per token: <=4 nonzero stores + l_aux.
__global__ __launch_bounds__(256) void tg_scatter(float* __restrict__ out,
                                                  const int* __restrict__ wsi)
{
    const float* wsf = (const float*)wsi;
    const int s = blockIdx.x * 256 + threadIdx.x;   // 0..8191
    const int pk = wsi[PKO + s];
    const int c  = s >> 6;                          // CHK=64
    const int i1 = pk & 255, i2 = (pk >> 8) & 255;
    const unsigned b1w = (unsigned)wsi[B12O + c * NEXP + i1];
    const unsigned b2w = (unsigned)wsi[B12O + c * NEXP + i2];
    const int loc1 = (int)(b1w & 0xffffu) + ((pk >> 16) & 255);
    const int loc2 = (int)(b2w >> 16)     + ((pk >> 24) & 255);
    const bool k1 = loc1 < CAPC, k2 = loc2 < CAPC;
    const float g1 = wsf[G1O + s], g2 = wsf[G2O + s];
    const float ge1 = k1 ? g1 : 0.f, ge2 = k2 ? g2 : 0.f;
    const float dn  = fmaxf(ge1 + ge2, EPSF);       // post-drop renormalization
    const long long cb = 1 + (long long)s * TBLK;   // combine token block
    if (k1) { out[cb + i1 * CAPC + loc1] = ge1 / dn; out[cb + SEC + i1 * CAPC + loc1] = 1.f; }
    if (k2) { out[cb + i2 * CAPC + loc2] = ge2 / dn; out[cb + SEC + i2 * CAPC + loc2] = 1.f; }
    if (s == 0) out[0] = wsf[LAUX];                 // l_aux
}

extern "C" void kernel_launch(void* const* d_in, const int* in_sizes, int n_in,
                              void* d_out, int out_size, void* d_ws, size_t ws_size,
                              hipStream_t stream)
{
    (void)ws_size; (void)in_sizes; (void)n_in; (void)out_size;
    const float* logits = (const float*)d_in[0];
    const float* noise  = (const float*)d_in[1];
    float* out = (float*)d_out;
    int*   wsi = (int*)d_ws;
    float* wsf = (float*)d_ws;

    tg_gate     <<<NCHK,        512, 0, stream>>>(logits, noise, wsi, wsf);
    tg_scan     <<<1,           256, 0, stream>>>(wsi, wsf);
    tg_fill     <<<FILL_BLOCKS, 256, 0, stream>>>(out);
    tg_fill_tail<<<FILL_BLOCKS, 256, 0, stream>>>(out);
    tg_scatter  <<<TOK / 256,   256, 0, stream>>>(out, wsi);
}

// Round 17
// 221.293 us; speedup vs baseline: 1.6857x; 1.6857x over previous
//
#include <hip/hip_runtime.h>

// Top2Gating, S=8192, E=64, capacity=256. Output f32 flat, NATURAL layout:
//   [ l_aux (1) | combine (S*E*CAP) | dispatch (S*E*CAP) ] = 1 + 2*SEC words.
// 4-kernel pipeline, scratch in d_ws (~200KB):
//   gate -> PK/G1/G2/H12/ME tables; scan -> B12 bases + l_aux;
//   zero -> PURE wave-contiguous NT zero of the whole output (no loads/branches/waits);
//   scatter -> <=4 nonzero stores per token + l_aux (after zero, kernel-boundary order).

namespace {
constexpr int  TOK  = 8192;
constexpr int  NEXP = 64;
constexpr int  CAPC = 256;
constexpr int  CHK  = 64;                           // one wave per chunk rank-phase
constexpr int  NCHK = TOK / CHK;                    // 128
constexpr long long TBLK = (long long)NEXP * CAPC;  // 16384 words per token block
constexpr long long SEC  = (long long)TOK * TBLK;   // words per dense section
constexpr float NEGMIN = -3.402823466e38f;          // finfo(f32).min
constexpr float EPSF   = 1.1920929e-7f;             // finfo(f32).eps
// d_ws word offsets
constexpr int PKO  = 0;          // pk[8192]  = i1|i2<<8|r1<<16|r2<<24
constexpr int G1O  = 8192;       // gate1[8192]
constexpr int G2O  = 16384;      // gate2[8192]
constexpr int H12O = 24576;      // (h1|h2<<16)[128*64]
constexpr int MEO  = 32768;      // me[128*64]
constexpr int B12O = 40960;      // (b1|b2full<<16)[128*64]
constexpr int LAUX = 49152;      // l_aux scalar
}

typedef float f32x4 __attribute__((ext_vector_type(4)));

__device__ __forceinline__ float wave_max64(float v) {
    for (int o = 32; o; o >>= 1) v = fmaxf(v, __shfl_xor(v, o));
    return v;
}
__device__ __forceinline__ float wave_sum64(float v) {
    for (int o = 32; o; o >>= 1) v += __shfl_xor(v, o);
    return v;
}

// ---- Phase 1: gating + one-wave ballot-match ranks. 128 blocks x 512 threads.
__global__ __launch_bounds__(512) void tg_gate(const float* __restrict__ logits,
                                               const float* __restrict__ noise,
                                               int* __restrict__ wsi,
                                               float* __restrict__ wsf)
{
    __shared__ int   i12s[CHK];
    __shared__ float g1s[CHK], g2s[CHK];
    __shared__ int   lr1s[CHK], lr2s[CHK];
    __shared__ int   cnt[2][NEXP];
    __shared__ float meSh[512];
    const int tid = threadIdx.x, lane = tid & 63, wv = tid >> 6;   // 8 waves
    const int c = blockIdx.x;

    if (tid < 128) cnt[tid >> 6][tid & 63] = 0;

    float meAcc = 0.f;
    #pragma unroll
    for (int i = 0; i < CHK / 8; ++i) {             // 8 rows per wave
        const int rloc = i * 8 + wv;
        const int row  = c * CHK + rloc;
        const float l = logits[row * NEXP + lane];
        const float n = noise [row * NEXP + lane];

        const float m    = wave_max64(l);
        const float ex   = __expf(l - m);
        const float sm   = wave_sum64(ex);
        const float gate = ex / sm;

        const unsigned long long b1 = __ballot(l == m);     // argmax(gates)==argmax(logits)
        const int   i1 = __ffsll(b1) - 1;                   // first max wins
        const float G1 = __shfl(gate, i1);

        const float lw = (lane == i1) ? NEGMIN : (l + n);   // mask winner with finfo.min
        const float m2 = wave_max64(lw);
        const unsigned long long b2 = __ballot(lw == m2);
        const int   i2 = __ffsll(b2) - 1;
        const float G2 = __shfl(gate, i2);

        if (lane == 0) {
            i12s[rloc] = i1 | (i2 << 8);
            g1s[rloc]  = G1;
            g2s[rloc]  = G2;
        }
        meAcc += gate;
    }
    meSh[tid] = meAcc;
    __syncthreads();

    // match phase: wave 0 = first choice, wave 1 = second; chunk == one wave.
    if (wv < 2) {
        const int sel = wv;
        const int pk  = i12s[lane];
        const int e   = sel ? ((pk >> 8) & 255) : (pk & 255);
        unsigned long long m = ~0ull;
        #pragma unroll
        for (int b = 0; b < 6; ++b) {
            const unsigned long long bb = __ballot((e >> b) & 1);
            m &= ((e >> b) & 1) ? bb : ~bb;         // lanes choosing same expert
        }
        const unsigned long long below = (1ull << lane) - 1;
        (sel ? lr2s : lr1s)[lane] = __popcll(m & below);    // rank among earlier tokens
        if ((m & below) == 0) cnt[sel][e] = __popcll(m);    // leader records group size
    }
    __syncthreads();

    if (tid < CHK) {
        const int pk = i12s[tid];
        wsi[PKO + c * CHK + tid] = (pk & 0xffff) | (lr1s[tid] << 16) | (lr2s[tid] << 24);
        wsf[G1O + c * CHK + tid] = g1s[tid];
        wsf[G2O + c * CHK + tid] = g2s[tid];
    }
    if (tid < NEXP) {
        wsi[H12O + c * NEXP + tid] = cnt[0][tid] | (cnt[1][tid] << 16);
        float s = 0.f;
        #pragma unroll
        for (int w = 0; w < 8; ++w) s += meSh[w * 64 + tid];
        wsf[MEO + c * NEXP + tid] = s;
    }
}

// ---- Phase 2: PARALLEL cross-chunk scan. 256 threads = 4 quarters x 64 experts.
__global__ __launch_bounds__(256) void tg_scan(int* __restrict__ wsi,
                                               float* __restrict__ wsf)
{
    __shared__ int   s1[4][NEXP], s2[4][NEXP];
    __shared__ float sm[4][NEXP];
    const int tid = threadIdx.x, e = tid & 63, q = tid >> 6;

    int t1 = 0, t2 = 0;
    float ms = 0.f;
    #pragma unroll
    for (int i = 0; i < NCHK / 4; ++i) {            // quarter totals (32 indep loads)
        const int c = q * (NCHK / 4) + i;
        const int h = wsi[H12O + c * NEXP + e];
        t1 += h & 0xffff;
        t2 += h >> 16;
        ms += wsf[MEO + c * NEXP + e];
    }
    s1[q][e] = t1; s2[q][e] = t2; sm[q][e] = ms;
    __syncthreads();

    int off1 = 0, off2 = 0, T1 = 0;
    float MS = 0.f;
    #pragma unroll
    for (int qq = 0; qq < 4; ++qq) {                // exclusive quarter offsets + totals
        if (qq < q) { off1 += s1[qq][e]; off2 += s2[qq][e]; }
        T1 += s1[qq][e];
        MS += sm[qq][e];
    }

    int p1 = off1, p2 = T1 + off2;                  // b2full = excl prefix2 + tot1
    #pragma unroll
    for (int i = 0; i < NCHK / 4; ++i) {            // write bases (re-reads L2-hot)
        const int c = q * (NCHK / 4) + i;
        const int h = wsi[H12O + c * NEXP + e];
        wsi[B12O + c * NEXP + e] = p1 | (p2 << 16);
        p1 += h & 0xffff;
        p2 += h >> 16;
    }

    if (q == 0) {                                   // l_aux scalar
        float term = (MS * (1.f / TOK)) * ((float)T1 * (1.f / TOK)) * (float)(NEXP * NEXP);
        term = wave_sum64(term);
        if (e == 0) wsf[LAUX] = term * (1.f / NEXP);
    }
}

// ---- Phase 3: PURE zero writer. One wave per contiguous 64KB window; nothing
//      but 64 NT quad-stores per lane. Covers words [0, 2*SEC); final word
//      (index 2*SEC) by one designated lane (different address, no drain needed).
__global__ __launch_bounds__(256) void tg_zero(float* __restrict__ out)
{
    const int lane = threadIdx.x & 63, wv = threadIdx.x >> 6;
    const int w = blockIdx.x * 4 + wv;              // 0..16383
    f32x4* b4 = (f32x4*)out + (long long)w * 4096;  // own 64KB window
    const f32x4 z = {0.f, 0.f, 0.f, 0.f};
    #pragma unroll
    for (int i = 0; i < 64; ++i)
        __builtin_nontemporal_store(z, &b4[i * 64 + lane]);
    if (w == 16383 && lane == 0) out[2 * SEC] = 0.f;    // buffer's last word
}

// ---- Phase 4: scatter. One thread per token: <=4 nonzero stores + l_aux.
__global__ __launch_bounds__(256) void tg_scatter(float* __restrict__ out,
                                                  const int* __restrict__ wsi)
{
    const float* wsf = (const float*)wsi;
    const int s = blockIdx.x * 256 + threadIdx.x;   // 0..8191
    const int pk = wsi[PKO + s];
    const int c  = s >> 6;                          // CHK=64
    const int i1 = pk & 255, i2 = (pk >> 8) & 255;
    const unsigned b1w = (unsigned)wsi[B12O + c * NEXP + i1];
    const unsigned b2w = (unsigned)wsi[B12O + c * NEXP + i2];
    const int loc1 = (int)(b1w & 0xffffu) + ((pk >> 16) & 255);
    const int loc2 = (int)(b2w >> 16)     + ((pk >> 24) & 255);
    const bool k1 = loc1 < CAPC, k2 = loc2 < CAPC;
    const float g1 = wsf[G1O + s], g2 = wsf[G2O + s];
    const float ge1 = k1 ? g1 : 0.f, ge2 = k2 ? g2 : 0.f;
    const float dn  = fmaxf(ge1 + ge2, EPSF);       // post-drop renormalization
    const long long cb = 1 + (long long)s * TBLK;   // combine token block
    if (k1) { out[cb + i1 * CAPC + loc1] = ge1 / dn; out[cb + SEC + i1 * CAPC + loc1] = 1.f; }
    if (k2) { out[cb + i2 * CAPC + loc2] = ge2 / dn; out[cb + SEC + i2 * CAPC + loc2] = 1.f; }
    if (s == 0) out[0] = wsf[LAUX];                 // l_aux
}

extern "C" void kernel_launch(void* const* d_in, const int* in_sizes, int n_in,
                              void* d_out, int out_size, void* d_ws, size_t ws_size,
                              hipStream_t stream)
{
    (void)ws_size; (void)in_sizes; (void)n_in; (void)out_size;
    const float* logits = (const float*)d_in[0];
    const float* noise  = (const float*)d_in[1];
    float* out = (float*)d_out;
    int*   wsi = (int*)d_ws;
    float* wsf = (float*)d_ws;

    tg_gate   <<<NCHK,      512, 0, stream>>>(logits, noise, wsi, wsf);
    tg_scan   <<<1,         256, 0, stream>>>(wsi, wsf);
    tg_zero   <<<TOK / 2,   256, 0, stream>>>(out);     // 4096 blocks, 4 windows each
    tg_scatter<<<TOK / 256, 256, 0, stream>>>(out, wsi);
}

// Round 18
// 209.969 us; speedup vs baseline: 1.7766x; 1.0539x over previous
//
#include <hip/hip_runtime.h>

// Top2Gating, S=8192, E=64, capacity=256. Output f32 flat:
//   [ l_aux (1) | combine (S*E*CAP) | dispatch (S*E*CAP) ] = 1 + 2*SEC words.
// Window design: output = 16384 windows of 16384 words at w*TBLK (64KB-aligned).
// Window w word 0 ("straddle") = previous token-block's last element (l_aux for w=0).
// gate -> scan(parallel) -> emit(records+straddles) -> write.
// write (one WAVE per window): NT bulk stream of words [256,16K) issues
// immediately (no alias with the record load of words 0..4); then one fused
// record-dependent f32x4 per lane covers words 0..255; conditional vmcnt+patch
// for nonzeros >= 256. Best-measured configuration (210.1us, = R12's 210.2).
// Compact scratch in windows 16377..16382 words [8..): consumed by emit; zeroed by write.

namespace {
constexpr int  TOK  = 8192;
constexpr int  NEXP = 64;
constexpr int  CAPC = 256;
constexpr int  CHK  = 64;                           // one wave per chunk rank-phase
constexpr int  NCHK = TOK / CHK;                    // 128
constexpr long long TBLK = (long long)NEXP * CAPC;  // 16384 words per window
constexpr long long SEC  = (long long)TOK * TBLK;   // words per dense section
constexpr float NEGMIN = -3.402823466e38f;          // finfo(f32).min
constexpr float EPSF   = 1.1920929e-7f;             // finfo(f32).eps
constexpr long long PK_OFF  = 16377LL * TBLK + 8;   // pk  = i1|i2<<8|r1<<16|r2<<24
constexpr long long G1_OFF  = 16378LL * TBLK + 8;   // gate1 value
constexpr long long G2_OFF  = 16379LL * TBLK + 8;   // gate2 value
constexpr long long H12_OFF = 16380LL * TBLK + 8;   // h1 | h2<<16 per (chunk,expert)
constexpr long long ME_OFF  = 16381LL * TBLK + 8;   // me partial per (chunk,expert)
constexpr long long B12_OFF = 16382LL * TBLK + 8;   // b1 | b2full<<16 per (chunk,expert)
// per-window record (words w*TBLK + 0..4), written by emit, read by write:
//   [0] straddle FINAL value  [1] rec0=i1|i2<<8|k1<<16|k2<<17
//   [2] rec1=loc1|loc2<<16    [3] v1  [4] v2
}

typedef float f32x4 __attribute__((ext_vector_type(4)));

__device__ __forceinline__ float wave_max64(float v) {
    for (int o = 32; o; o >>= 1) v = fmaxf(v, __shfl_xor(v, o));
    return v;
}
__device__ __forceinline__ float wave_sum64(float v) {
    for (int o = 32; o; o >>= 1) v += __shfl_xor(v, o);
    return v;
}

// ---- Phase 1: gating + one-wave ballot-match ranks. 128 blocks x 512 threads.
__global__ __launch_bounds__(512) void tg_gate(const float* __restrict__ logits,
                                               const float* __restrict__ noise,
                                               float* __restrict__ out)
{
    __shared__ int   i12s[CHK];
    __shared__ float g1s[CHK], g2s[CHK];
    __shared__ int   lr1s[CHK], lr2s[CHK];
    __shared__ int   cnt[2][NEXP];
    __shared__ float meSh[512];
    const int tid = threadIdx.x, lane = tid & 63, wv = tid >> 6;   // 8 waves
    const int c = blockIdx.x;

    if (tid < 128) cnt[tid >> 6][tid & 63] = 0;

    float meAcc = 0.f;
    #pragma unroll
    for (int i = 0; i < CHK / 8; ++i) {             // 8 rows per wave
        const int rloc = i * 8 + wv;
        const int row  = c * CHK + rloc;
        const float l = logits[row * NEXP + lane];
        const float n = noise [row * NEXP + lane];

        const float m    = wave_max64(l);
        const float ex   = __expf(l - m);
        const float sm   = wave_sum64(ex);
        const float gate = ex / sm;

        const unsigned long long b1 = __ballot(l == m);     // argmax(gates)==argmax(logits)
        const int   i1 = __ffsll(b1) - 1;                   // first max wins
        const float G1 = __shfl(gate, i1);

        const float lw = (lane == i1) ? NEGMIN : (l + n);   // mask winner with finfo.min
        const float m2 = wave_max64(lw);
        const unsigned long long b2 = __ballot(lw == m2);
        const int   i2 = __ffsll(b2) - 1;
        const float G2 = __shfl(gate, i2);

        if (lane == 0) {
            i12s[rloc] = i1 | (i2 << 8);
            g1s[rloc]  = G1;
            g2s[rloc]  = G2;
        }
        meAcc += gate;
    }
    meSh[tid] = meAcc;
    __syncthreads();

    // match phase: wave 0 = first choice, wave 1 = second; chunk == one wave.
    if (wv < 2) {
        const int sel = wv;
        const int pk  = i12s[lane];
        const int e   = sel ? ((pk >> 8) & 255) : (pk & 255);
        unsigned long long m = ~0ull;
        #pragma unroll
        for (int b = 0; b < 6; ++b) {
            const unsigned long long bb = __ballot((e >> b) & 1);
            m &= ((e >> b) & 1) ? bb : ~bb;         // lanes choosing same expert
        }
        const unsigned long long below = (1ull << lane) - 1;
        (sel ? lr2s : lr1s)[lane] = __popcll(m & below);    // rank among earlier tokens
        if ((m & below) == 0) cnt[sel][e] = __popcll(m);    // leader records group size
    }
    __syncthreads();

    int* outi = (int*)out;
    if (tid < CHK) {
        const int pk = i12s[tid];
        outi[PK_OFF + c * CHK + tid] = (pk & 0xffff) | (lr1s[tid] << 16) | (lr2s[tid] << 24);
        out [G1_OFF + c * CHK + tid] = g1s[tid];
        out [G2_OFF + c * CHK + tid] = g2s[tid];
    }
    if (tid < NEXP) {
        outi[H12_OFF + c * NEXP + tid] = cnt[0][tid] | (cnt[1][tid] << 16);
        float s = 0.f;
        #pragma unroll
        for (int w = 0; w < 8; ++w) s += meSh[w * 64 + tid];
        out[ME_OFF + c * NEXP + tid] = s;
    }
}

// ---- Phase 2: PARALLEL cross-chunk scan. 256 threads = 4 quarters x 64 experts.
__global__ __launch_bounds__(256) void tg_scan(float* __restrict__ out)
{
    __shared__ int   s1[4][NEXP], s2[4][NEXP];
    __shared__ float sm[4][NEXP];
    const int tid = threadIdx.x, e = tid & 63, q = tid >> 6;
    const int* outi = (const int*)out;

    int t1 = 0, t2 = 0;
    float ms = 0.f;
    #pragma unroll
    for (int i = 0; i < NCHK / 4; ++i) {            // quarter totals (32 indep loads)
        const int c = q * (NCHK / 4) + i;
        const int h = outi[H12_OFF + c * NEXP + e];
        t1 += h & 0xffff;
        t2 += h >> 16;
        ms += out[ME_OFF + c * NEXP + e];
    }
    s1[q][e] = t1; s2[q][e] = t2; sm[q][e] = ms;
    __syncthreads();

    int off1 = 0, off2 = 0, T1 = 0;
    float MS = 0.f;
    #pragma unroll
    for (int qq = 0; qq < 4; ++qq) {                // exclusive quarter offsets + totals
        if (qq < q) { off1 += s1[qq][e]; off2 += s2[qq][e]; }
        T1 += s1[qq][e];
        MS += sm[qq][e];
    }

    int p1 = off1, p2 = T1 + off2;                  // b2full = excl prefix2 + tot1
    int* wbi = (int*)out;
    #pragma unroll
    for (int i = 0; i < NCHK / 4; ++i) {            // write bases (re-reads are L2-hot)
        const int c = q * (NCHK / 4) + i;
        const int h = outi[H12_OFF + c * NEXP + e];
        wbi[B12_OFF + c * NEXP + e] = p1 | (p2 << 16);
        p1 += h & 0xffff;
        p2 += h >> 16;
    }

    if (q == 0) {                                   // l_aux (window 0 straddle)
        float term = (MS * (1.f / TOK)) * ((float)T1 * (1.f / TOK)) * (float)(NEXP * NEXP);
        term = wave_sum64(term);
        if (e == 0) out[0] = term * (1.f / NEXP);
    }
}

// ---- Phase 3: per-token finalize -> records (words 1..4) + straddles (word 0 of
//      next window; s=8191 dispatch case lands exactly on the buffer's last word).
__global__ __launch_bounds__(256) void tg_emit(float* __restrict__ out)
{
    const int s = blockIdx.x * 256 + threadIdx.x;   // one thread per token
    const int c = s >> 6;                           // CHK=64
    const int* outi = (const int*)out;
    const int   pk = outi[PK_OFF + s];
    const float G1 = out[G1_OFF + s];
    const float G2 = out[G2_OFF + s];
    const int i1 = pk & 255, i2 = (pk >> 8) & 255;
    const unsigned b1w = (unsigned)outi[B12_OFF + c * NEXP + i1];
    const unsigned b2w = (unsigned)outi[B12_OFF + c * NEXP + i2];
    const int loc1 = (int)(b1w & 0xffffu) + ((pk >> 16) & 255);
    const int loc2 = (int)(b2w >> 16)     + ((pk >> 24) & 255);

    const bool k1 = loc1 < CAPC, k2 = loc2 < CAPC;
    const float ge1 = k1 ? G1 : 0.f, ge2 = k2 ? G2 : 0.f;
    const float dn  = fmaxf(ge1 + ge2, EPSF);       // post-drop renormalization
    const float w1 = ge1 / dn, w2 = ge2 / dn;
    const int rec0 = i1 | (i2 << 8) | (k1 ? 1 << 16 : 0) | (k2 ? 1 << 17 : 0);
    const int rec1 = (k1 ? loc1 : 0) | ((k2 ? loc2 : 0) << 16);
    const int j1 = k1 ? (i1 * CAPC + loc1 + 1) : -1;   // window-local word, 1..16384
    const int j2 = k2 ? (i2 * CAPC + loc2 + 1) : -1;

    long long h = (long long)s * TBLK;              // combine window
    ((int*)out)[h + 1] = rec0;
    ((int*)out)[h + 2] = rec1;
    out[h + 3] = w1;
    out[h + 4] = w2;
    out[h + TBLK] = (j1 == (int)TBLK) ? w1 : ((j2 == (int)TBLK) ? w2 : 0.f);

    h = (long long)(TOK + s) * TBLK;                // dispatch window
    ((int*)out)[h + 1] = rec0;
    ((int*)out)[h + 2] = rec1;
    out[h + 3] = 1.f;
    out[h + 4] = 1.f;
    out[h + TBLK] = (j1 == (int)TBLK || j2 == (int)TBLK) ? 1.f : 0.f;
}

// ---- Phase 4: dense writer, one WAVE per window. NT bulk stream of words
//      [256,16K) first (no alias with record load -> issues immediately), then
//      fused head f32x4 (words 0..255), then conditional drain + scatter.
__global__ __launch_bounds__(256) void tg_write(float* __restrict__ out)
{
    const int lane = threadIdx.x & 63, wv = threadIdx.x >> 6;
    const int w = blockIdx.x * 4 + wv;              // 0..16383
    float* base = out + (long long)w * TBLK;        // 64KB-aligned
    f32x4* b4 = (f32x4*)base;

    const f32x4 A  = *(const f32x4*)base;           // words 0..3 (record)
    const float v2 = base[4];

    // bulk NT zero stream: words [256, 16384) -- independent of the record load
    const f32x4 z = {0.f, 0.f, 0.f, 0.f};
    #pragma unroll
    for (int i = 1; i < 64; ++i)
        __builtin_nontemporal_store(z, &b4[i * 64 + lane]);

    const float sv  = A.x;
    const int  rec0 = __float_as_int(A.y);
    const int  rec1 = __float_as_int(A.z);
    const float v1  = A.w;
    const bool k1 = (rec0 >> 16) & 1, k2 = (rec0 >> 17) & 1;
    const int  i1 = rec0 & 255, i2 = (rec0 >> 8) & 255;
    const int  j1 = k1 ? (i1 * CAPC + (rec1 & 0xffff) + 1) : -1;  // 1..16384 or -1
    const int  j2 = k2 ? (i2 * CAPC + (rec1 >> 16) + 1) : -1;

    // fused head block: words 0..255, one record-dependent f32x4 per lane
    {
        const int q = lane * 4;
        f32x4 v;
        v.x = (q     == j1) ? v1 : ((q     == j2) ? v2 : 0.f);
        v.y = (q + 1 == j1) ? v1 : ((q + 1 == j2) ? v2 : 0.f);
        v.z = (q + 2 == j1) ? v1 : ((q + 2 == j2) ? v2 : 0.f);
        v.w = (q + 3 == j1) ? v1 : ((q + 3 == j2) ? v2 : 0.f);
        if (lane == 0) v.x = sv;                    // straddle / l_aux
        __builtin_nontemporal_store(v, &b4[lane]);
    }

    // scattered nonzeros in the streamed region (same-address store ordering)
    if (j1 >= 256 || j2 >= 256) {
        asm volatile("s_waitcnt vmcnt(0)" ::: "memory");
        if (lane == 0) {
            if (k1 && j1 >= 256 && j1 < (int)TBLK) base[j1] = v1;
            if (k2 && j2 >= 256 && j2 < (int)TBLK) base[j2] = v2;
        }
    }
}

extern "C" void kernel_launch(void* const* d_in, const int* in_sizes, int n_in,
                              void* d_out, int out_size, void* d_ws, size_t ws_size,
                              hipStream_t stream)
{
    (void)d_ws; (void)ws_size; (void)in_sizes; (void)n_in; (void)out_size;
    const float* logits = (const float*)d_in[0];
    const float* noise  = (const float*)d_in[1];
    float* out = (float*)d_out;

    tg_gate <<<NCHK,      512, 0, stream>>>(logits, noise, out);
    tg_scan <<<1,         256, 0, stream>>>(out);
    tg_emit <<<TOK / 256, 256, 0, stream>>>(out);
    tg_write<<<TOK / 2,   256, 0, stream>>>(out);   // 4096 blocks, 4 windows each
}